// Round 1
// baseline (292.510 us; speedup 1.0000x reference)
//
#include <hip/hip_runtime.h>

#define NHh 16

typedef unsigned short ushortT;
typedef __attribute__((ext_vector_type(8))) short short8;
typedef __attribute__((ext_vector_type(4))) float floatx4;

__device__ __forceinline__ ushortT f2bf(float x) {
    union { float f; unsigned int u; } cv; cv.f = x;
    unsigned int u = cv.u;
    unsigned int r = u + 0x7fffu + ((u >> 16) & 1u);
    return (ushortT)(r >> 16);
}

// truncating pack of two fp32 -> packed bf16x2 (cheap; used for P which is in [0,1])
__device__ __forceinline__ unsigned pack2_trunc(float a, float b) {
    union { float f; unsigned u; } ua, ub;
    ua.f = a; ub.f = b;
    return (ub.u & 0xffff0000u) | (ua.u >> 16);
}

__device__ __forceinline__ void gload_lds16(const ushortT* g, ushortT* l) {
    __builtin_amdgcn_global_load_lds(
        (const __attribute__((address_space(1))) void*)g,
        (__attribute__((address_space(3))) void*)l, 16, 0, 0);
}

// ---------------- fp32 -> bf16 converters ----------------
__global__ __launch_bounds__(256) void cvt_x(const float* __restrict__ in,
                                             ushortT* __restrict__ out, int n4) {
    int i = blockIdx.x * 256 + threadIdx.x;
    if (i >= n4) return;
    float4 f = ((const float4*)in)[i];
    uint2 o;
    o.x = (unsigned)f2bf(f.x) | ((unsigned)f2bf(f.y) << 16);
    o.y = (unsigned)f2bf(f.z) | ((unsigned)f2bf(f.w) << 16);
    ((uint2*)out)[i] = o;
}

__global__ __launch_bounds__(256) void cvt_w(const float* __restrict__ W0, const float* __restrict__ W1,
                                             const float* __restrict__ W2, const float* __restrict__ W3,
                                             ushortT* __restrict__ o0, ushortT* __restrict__ o1,
                                             ushortT* __restrict__ o2, ushortT* __restrict__ o3, int n4) {
    int z = blockIdx.y;
    const float* in = (z == 0) ? W0 : (z == 1) ? W1 : (z == 2) ? W2 : W3;
    ushortT* out = (z == 0) ? o0 : (z == 1) ? o1 : (z == 2) ? o2 : o3;
    int i = blockIdx.x * 256 + threadIdx.x;
    if (i >= n4) return;
    float4 f = ((const float4*)in)[i];
    uint2 o;
    o.x = (unsigned)f2bf(f.x) | ((unsigned)f2bf(f.y) << 16);
    o.y = (unsigned)f2bf(f.z) | ((unsigned)f2bf(f.w) << 16);
    ((uint2*)out)[i] = o;
}

// ---------------- 256x256 8-phase QKV GEMM (T2 swizzle + T3/T4 counted vmcnt + T5) ----
// LDS tile layout: [16 rowblk][2 colblk(=k-slice)][16 r][32 col] bf16, byte-swizzled
//   o_logical = o ^ (((o>>9)&1)<<5)   (st_16x32: chunk ^= (r>>3)<<1)
// read of frag (row=base+ln, kslice ks, 16B chunk qd):
__device__ __forceinline__ short8 lds_frag(const ushortT* tb, int row, int ks, int qd) {
    int rowblk = row >> 4;
    int r = row & 15;
    int c2 = qd ^ ((r >> 3) << 1);
    return *(const short8*)((const char*)tb + rowblk * 2048 + ks * 1024 + r * 64 + c2 * 16);
}

// grid 384: l>>7 = z (0:Q 1:K 2:V).  z<2: A=X (32 m-tiles), B=W (4 n-tiles);
// z==2: A=Wv (4 m-tiles), B=X (32 n-tiles) -> C = V^T.
// 8 waves (2Mx4N); wave frags interleaved: m-frag mi at rows mi*32+wr*16,
// n-frag ni at cols ni*64+wc*16  -> phase (mq,nq) touches exactly A-half mq / B-half nq.
__global__ __launch_bounds__(512, 2) void qkv256(
        const ushortT* __restrict__ X,
        const ushortT* __restrict__ W0, const ushortT* __restrict__ W1, const ushortT* __restrict__ W2,
        const float* __restrict__ b0, const float* __restrict__ b1, const float* __restrict__ b2,
        ushortT* __restrict__ Qo, ushortT* __restrict__ Ko, ushortT* __restrict__ Vo) {
    __shared__ __align__(16) ushortT As[2 * 16384];   // 64 KB (2 bufs x 256x64)
    __shared__ __align__(16) ushortT Bs[2 * 16384];   // 64 KB

    const int l = blockIdx.x;
    const int z = l >> 7;
    const int idx = l & 127;
    const int tid = threadIdx.x;
    const int lane = tid & 63;
    const int w = tid >> 6;
    const int wr = w >> 2;        // 0..1
    const int wc = w & 3;         // 0..3
    const int qd = lane >> 4;
    const int ln = lane & 15;

    const ushortT* Ap; const ushortT* Bp;
    int arow0, brow0;
    if (z == 2) { Ap = W2; arow0 = (idx & 3) * 256; Bp = X; brow0 = (idx >> 2) * 256; }
    else { Ap = X; arow0 = (idx >> 2) * 256; Bp = (z == 0) ? W0 : W1; brow0 = (idx & 3) * 256; }

    floatx4 acc[8][4];
#pragma unroll
    for (int i = 0; i < 8; i++)
#pragma unroll
        for (int j = 0; j < 4; j++) acc[i][j] = (floatx4){0.f, 0.f, 0.f, 0.f};

    // stage one half-tile (cursor: kt = c>>2, half c&3: 0=A0 1=A1 2=B0 3=B1); 2x16B/thread
    auto STAGE = [&](int cursor) {
        int kt = cursor >> 2;
        if (kt >= 16) return;
        int h = cursor & 3;
        int buf = kt & 1;
        int k0 = kt << 6;
        const ushortT* G = (h < 2) ? Ap : Bp;
        int row0 = (h < 2) ? arow0 : brow0;
        ushortT* L = (h < 2) ? (As + buf * 16384) : (Bs + buf * 16384);
        int half = h & 1;
#pragma unroll
        for (int j = 0; j < 2; j++) {
            int o = half * 16384 + j * 8192 + tid * 16;         // linear LDS byte dest
            int rowblk = o >> 11;
            int colblk = (o >> 10) & 1;
            int r = (o >> 6) & 15;
            int c2 = ((o >> 4) & 3) ^ ((r >> 3) << 1);          // inverse-swizzled source chunk
            gload_lds16(G + (size_t)(row0 + rowblk * 16 + r) * 1024 + k0 + colblk * 32 + c2 * 8,
                        (ushortT*)((char*)L + o));
        }
    };

    // prologue: K0 (4 half-tiles) + 3 of K1; vmcnt(6) -> K0 landed, 3 in flight
    for (int c = 0; c < 7; c++) STAGE(c);
    asm volatile("s_waitcnt vmcnt(6)" ::: "memory");
    __builtin_amdgcn_s_barrier();

    short8 afr[4][2], bfr[2][2];
    int cursor = 7;
    for (int T = 0; T < 16; T++) {
        const ushortT* Ab = As + (T & 1) * 16384;
        const ushortT* Bb = Bs + (T & 1) * 16384;
#pragma unroll
        for (int ph = 0; ph < 4; ph++) {
            const int mq = ph >> 1, nq = ph & 1;
            // ds reads for this quadrant (B every phase; A on nq==0, reused at nq==1)
#pragma unroll
            for (int ni = 0; ni < 2; ni++)
#pragma unroll
                for (int ks = 0; ks < 2; ks++)
                    bfr[ni][ks] = lds_frag(Bb, nq * 128 + ni * 64 + wc * 16 + ln, ks, qd);
            if (nq == 0) {
#pragma unroll
                for (int mi = 0; mi < 4; mi++)
#pragma unroll
                    for (int ks = 0; ks < 2; ks++)
                        afr[mi][ks] = lds_frag(Ab, (mq * 4 + mi) * 32 + wr * 16 + ln, ks, qd);
            }
            STAGE(cursor); ++cursor;        // steady stagger: B1(T+1),A0(T+2),A1(T+2),B0(T+2)
            __builtin_amdgcn_s_barrier();
            asm volatile("s_waitcnt lgkmcnt(0)" ::: "memory");
            __builtin_amdgcn_s_setprio(1);
#pragma unroll
            for (int mi = 0; mi < 4; mi++)
#pragma unroll
                for (int ni = 0; ni < 2; ni++)
#pragma unroll
                    for (int ks = 0; ks < 2; ks++)
                        acc[mq * 4 + mi][nq * 2 + ni] =
                            __builtin_amdgcn_mfma_f32_16x16x32_bf16(afr[mi][ks], bfr[ni][ks],
                                                                    acc[mq * 4 + mi][nq * 2 + ni], 0, 0, 0);
            __builtin_amdgcn_s_setprio(0);
            if (ph == 3) {                  // once per K-tile: guarantee K-tile T+1 landed
                if (T < 14) { asm volatile("s_waitcnt vmcnt(6)" ::: "memory"); }
                else        { asm volatile("s_waitcnt vmcnt(0)" ::: "memory"); }
            }
            __builtin_amdgcn_s_barrier();
        }
    }

    // epilogue: C row (m) = qd*4+r2 side (A), col (n) = ln side (B)
    if (z == 2) {
        floatx4 bv4[8];
#pragma unroll
        for (int mi = 0; mi < 8; mi++)
            bv4[mi] = *(const floatx4*)(b2 + arow0 + mi * 32 + wr * 16 + qd * 4);
#pragma unroll
        for (int ni = 0; ni < 4; ni++) {
            int n = brow0 + ni * 64 + wc * 16 + ln;       // token
            int bb = n >> 10, s = n & 1023;
#pragma unroll
            for (int mi = 0; mi < 8; mi++) {
#pragma unroll
                for (int r2 = 0; r2 < 4; r2++) {
                    int dim = arow0 + mi * 32 + wr * 16 + qd * 4 + r2;
                    int hh = dim >> 6, dd = dim & 63;
                    Vo[((size_t)(bb * NHh + hh) * 64 + dd) * 1024 + s] =
                        f2bf(acc[mi][ni][r2] + bv4[mi][r2]);
                }
            }
        }
    } else {
        ushortT* Out = z ? Ko : Qo;
        const float* bias = z ? b1 : b0;
#pragma unroll
        for (int ni = 0; ni < 4; ni++) {
            int n = brow0 + ni * 64 + wc * 16 + ln;       // out dim
            float bb = bias[n];
            int h = n >> 6, d = n & 63;
#pragma unroll
            for (int mi = 0; mi < 8; mi++) {
#pragma unroll
                for (int r2 = 0; r2 < 4; r2++) {
                    int m = arow0 + mi * 32 + wr * 16 + qd * 4 + r2; // token
                    int b = m >> 10, s = m & 1023;
                    Out[(size_t)((b * NHh + h) * 1024 + s) * 64 + d] =
                        f2bf(acc[mi][ni][r2] + bb);
                }
            }
        }
    }
}

// ---------------- out-proj GEMM (fp32 out), 1-D grid 512: m=l%64, n=l/64 ----------------
__global__ __launch_bounds__(256) void oproj_gemm(const ushortT* __restrict__ A,
        const ushortT* __restrict__ Wt, const float* __restrict__ bias, float* __restrict__ Pj) {
    __shared__ ushortT As[128 * 32];
    __shared__ ushortT Bs[128 * 32];
    const int l = blockIdx.x;
    const int m0 = (l & 63) * 128;
    const int n0 = (l >> 6) * 128;
    const int tid = threadIdx.x;
    const int lane = tid & 63;
    const int w = tid >> 6;
    const int qd = lane >> 4;
    const int ln = lane & 15;
    const int RM = (w >> 1) * 64;
    const int RN = (w & 1) * 64;

    floatx4 acc[4][4];
#pragma unroll
    for (int i = 0; i < 4; i++)
#pragma unroll
        for (int j = 0; j < 4; j++) acc[i][j] = (floatx4){0.f, 0.f, 0.f, 0.f};

    const int c0 = tid, c1 = tid + 256;
    for (int k0 = 0; k0 < 1024; k0 += 32) {
        gload_lds16(A + (size_t)(m0 + (c0 >> 2)) * 1024 + k0 + (c0 & 3) * 8, As + c0 * 8);
        gload_lds16(A + (size_t)(m0 + (c1 >> 2)) * 1024 + k0 + (c1 & 3) * 8, As + c1 * 8);
        gload_lds16(Wt + (size_t)(n0 + (c0 >> 2)) * 1024 + k0 + (c0 & 3) * 8, Bs + c0 * 8);
        gload_lds16(Wt + (size_t)(n0 + (c1 >> 2)) * 1024 + k0 + (c1 & 3) * 8, Bs + c1 * 8);
        __syncthreads();
        short8 af[4], bf8[4];
#pragma unroll
        for (int i = 0; i < 4; i++) af[i] = *(const short8*)&As[(RM + i * 16 + ln) * 32 + qd * 8];
#pragma unroll
        for (int j = 0; j < 4; j++) bf8[j] = *(const short8*)&Bs[(RN + j * 16 + ln) * 32 + qd * 8];
#pragma unroll
        for (int i = 0; i < 4; i++)
#pragma unroll
            for (int j = 0; j < 4; j++)
                acc[i][j] = __builtin_amdgcn_mfma_f32_16x16x32_bf16(af[i], bf8[j], acc[i][j], 0, 0, 0);
        __syncthreads();
    }

#pragma unroll
    for (int j = 0; j < 4; j++) {
        int n = n0 + RN + j * 16 + ln;
        float bb = bias[n];
#pragma unroll
        for (int i = 0; i < 4; i++) {
#pragma unroll
            for (int r2 = 0; r2 < 4; r2++) {
                int m = m0 + RM + i * 16 + qd * 4 + r2;
                Pj[(size_t)m * 1024 + n] = acc[i][j][r2] + bb;
            }
        }
    }
}

// ---------------- flash attention: 256-q tile, LDS-staged K/V (XOR-swizzled) ----------------
__global__ __launch_bounds__(256, 2) void attn_kernel(const ushortT* __restrict__ Q,
        const ushortT* __restrict__ K, const ushortT* __restrict__ Vg_t,
        const float* __restrict__ mask, ushortT* __restrict__ ctx) {
    __shared__ __align__(16) ushortT Ks[128 * 64];      // 16 KB
    __shared__ __align__(16) ushortT Vt[64 * 128];      // 16 KB
    __shared__ __align__(16) ushortT Ps[4][64 * 72];    // 36 KB, per-wave [64 q][64 s + pad]

    const int tid = threadIdx.x;
    const int lane = tid & 63;
    const int w = tid >> 6;
    const int qd = lane >> 4;
    const int ln = lane & 15;
    const int l = blockIdx.x;
    const int bh = l & 127;
    const int b = bh >> 4;
    const int h = bh & 15;
    const int qb = l >> 7;

    const ushortT* Qg = Q + (size_t)bh * 65536;
    const ushortT* Kg = K + (size_t)bh * 65536;
    const ushortT* Vg = Vg_t + (size_t)bh * 65536;
    const float* mrow = mask + b * 1024;
    const float LOG2E = 1.4426950408889634f;
    const float SCL = 0.125f * 1.4426950408889634f;   // fold 1/sqrt(64) and log2e

    // resident Q B-fragments: q = qb*256 + w*64 + nj*16 + ln
    short8 qf[4][2];
#pragma unroll
    for (int nj = 0; nj < 4; nj++)
#pragma unroll
        for (int ks = 0; ks < 2; ks++)
            qf[nj][ks] = *(const short8*)(Qg + (size_t)(qb * 256 + w * 64 + nj * 16 + ln) * 64 + ks * 32 + qd * 8);

    float lst[4] = {0.f, 0.f, 0.f, 0.f};
    floatx4 accO[4][4];
#pragma unroll
    for (int i = 0; i < 4; i++)
#pragma unroll
        for (int j = 0; j < 4; j++) accO[i][j] = (floatx4){0.f, 0.f, 0.f, 0.f};

    // staging lane geometry
    const int ksr = lane >> 3;          // K: s-subrow within 8-row group
    const int kc  = lane & 7;           // K: chunk index (8 x 16B per 128B row)
    const int vdr = lane >> 4;          // V: d-subrow within 4-row group
    const int vcc = lane & 15;          // V: chunk index (16 x 16B per 256B row)

    for (int kt = 0; kt < 8; ++kt) {
        __syncthreads();   // all waves done reading Ks/Vt of kt-1

        // stage K tile [128 s][64 d], chunk g of row s at slot g^(s&7)
#pragma unroll
        for (int ii = 0; ii < 4; ii++) {
            int i = w * 4 + ii;
            int srow = i * 8 + ksr;
            gload_lds16(Kg + (size_t)(kt * 128 + srow) * 64 + (kc ^ ksr) * 8,
                        Ks + i * 512 + lane * 8);
        }
        // stage V^T tile [64 d][128 s], chunk g of row d at slot g^(d&15)
#pragma unroll
        for (int ii = 0; ii < 4; ii++) {
            int i = w * 4 + ii;
            int d = i * 4 + vdr;
            gload_lds16(Vg + (size_t)d * 1024 + kt * 128 + (vcc ^ (d & 15)) * 8,
                        Vt + i * 512 + lane * 8);
        }

        __syncthreads();   // tiles ready

#pragma unroll
        for (int h2 = 0; h2 < 2; ++h2) {
            const int s0g = kt * 128 + h2 * 64;

            // ---- S^T in nj-pairs (caps sv live regs at 32) ----
#pragma unroll
            for (int njp = 0; njp < 2; ++njp) {
                floatx4 sv[4][2];
#pragma unroll
                for (int mi = 0; mi < 4; mi++)
#pragma unroll
                    for (int j = 0; j < 2; j++) sv[mi][j] = (floatx4){0.f, 0.f, 0.f, 0.f};
#pragma unroll
                for (int ks = 0; ks < 2; ks++) {
                    short8 af[4];
#pragma unroll
                    for (int mi = 0; mi < 4; mi++)
                        af[mi] = *(const short8*)&Ks[(h2 * 64 + mi * 16 + ln) * 64 +
                                                     (((ks * 4 + qd) ^ (ln & 7)) * 8)];
#pragma unroll
                    for (int mi = 0; mi < 4; mi++)
#pragma unroll
                        for (int j = 0; j < 2; j++)
                            sv[mi][j] = __builtin_amdgcn_mfma_f32_16x16x32_bf16(af[mi], qf[njp * 2 + j][ks], sv[mi][j], 0, 0, 0);
                }

                // softmax-lite + per-wave Ps write
                float rs0 = 0.f, rs1 = 0.f;
#pragma unroll
                for (int mi = 0; mi < 4; mi++) {
                    floatx4 m4 = *(const floatx4*)(mrow + s0g + mi * 16 + qd * 4);
                    float p00 = __builtin_amdgcn_exp2f(sv[mi][0][0] * SCL + m4[0] * LOG2E);
                    float p01 = __builtin_amdgcn_exp2f(sv[mi][0][1] * SCL + m4[1] * LOG2E);
                    float p02 = __builtin_amdgcn_exp2f(sv[mi][0][2] * SCL + m4[2] * LOG2E);
                    float p03 = __builtin_amdgcn_exp2f(sv[mi][0][3] * SCL + m4[3] * LOG2E);
                    float p10 = __builtin_amdgcn_exp2f(sv[mi][1][0] * SCL + m4[0] * LOG2E);
                    float p11 = __builtin_amdgcn_exp2f(sv[mi][1][1] * SCL + m4[1] * LOG2E);
                    float p12 = __builtin_amdgcn_exp2f(sv[mi][1][2] * SCL + m4[2] * LOG2E);
                    float p13 = __builtin_amdgcn_exp2f(sv[mi][1][3] * SCL + m4[3] * LOG2E);
                    rs0 += (p00 + p01) + (p02 + p03);
                    rs1 += (p10 + p11) + (p12 + p13);
                    uint2 w0, w1;
                    w0.x = pack2_trunc(p00, p01); w0.y = pack2_trunc(p02, p03);
                    w1.x = pack2_trunc(p10, p11); w1.y = pack2_trunc(p12, p13);
                    *(uint2*)&Ps[w][(njp * 32 + ln) * 72 + mi * 16 + qd * 4] = w0;
                    *(uint2*)&Ps[w][(njp * 32 + 16 + ln) * 72 + mi * 16 + qd * 4] = w1;
                }
                rs0 += __shfl_xor(rs0, 16, 64); rs0 += __shfl_xor(rs0, 32, 64);
                rs1 += __shfl_xor(rs1, 16, 64); rs1 += __shfl_xor(rs1, 32, 64);
                lst[njp * 2 + 0] += rs0;
                lst[njp * 2 + 1] += rs1;
            }

            // ---- PV: A = P (per-wave LDS, 64 q rows), B = V^T (LDS, swizzled) ----
#pragma unroll
            for (int ks2 = 0; ks2 < 2; ks2++) {
                short8 ap[4], bv[4];
#pragma unroll
                for (int i = 0; i < 4; i++)
                    ap[i] = *(const short8*)&Ps[w][(i * 16 + ln) * 72 + ks2 * 32 + qd * 8];
#pragma unroll
                for (int j = 0; j < 4; j++)
                    bv[j] = *(const short8*)&Vt[(j * 16 + ln) * 128 +
                                                (((h2 * 8 + ks2 * 4 + qd) ^ ln) * 8)];
#pragma unroll
                for (int i = 0; i < 4; i++)
#pragma unroll
                    for (int j = 0; j < 4; j++)
                        accO[i][j] = __builtin_amdgcn_mfma_f32_16x16x32_bf16(ap[i], bv[j], accO[i][j], 0, 0, 0);
            }
        }
    }

    // epilogue: divide by l (lane transpose once) and store ctx [b][s=q][h*64+d]
#pragma unroll
    for (int i = 0; i < 4; i++) {
#pragma unroll
        for (int r = 0; r < 4; r++) {
            float lv = __shfl(lst[i], qd * 4 + r, 64);
            float linv = 1.f / lv;
            int q = qb * 256 + w * 64 + i * 16 + qd * 4 + r;
#pragma unroll
            for (int j = 0; j < 4; j++) {
                int d = j * 16 + ln;
                ctx[((size_t)(b * 1024 + q)) * 1024 + h * 64 + d] = f2bf(accO[i][j][r] * linv);
            }
        }
    }
}

// ---------------- residual + LayerNorm ----------------
__global__ __launch_bounds__(256) void ln_kernel(const float* __restrict__ Pj, const float* __restrict__ X,
        const float* __restrict__ gamma, const float* __restrict__ beta, float* __restrict__ out) {
    __shared__ float red[8];
    int row = blockIdx.x;
    int t = threadIdx.x;
    const float4 p4 = ((const float4*)(Pj + (size_t)row * 1024))[t];
    const float4 x4 = ((const float4*)(X + (size_t)row * 1024))[t];
    float r0 = p4.x + x4.x, r1 = p4.y + x4.y, r2 = p4.z + x4.z, r3 = p4.w + x4.w;
    float s = r0 + r1 + r2 + r3;
    float ss = r0 * r0 + r1 * r1 + r2 * r2 + r3 * r3;
#pragma unroll
    for (int o = 1; o < 64; o <<= 1) { s += __shfl_xor(s, o, 64); ss += __shfl_xor(ss, o, 64); }
    int w = t >> 6;
    if ((t & 63) == 0) { red[w] = s; red[4 + w] = ss; }
    __syncthreads();
    s = red[0] + red[1] + red[2] + red[3];
    ss = red[4] + red[5] + red[6] + red[7];
    float mu = s * (1.f / 1024.f);
    float var = ss * (1.f / 1024.f) - mu * mu;
    float inv = rsqrtf(var + 1e-12f);
    const float4 g4 = ((const float4*)gamma)[t];
    const float4 b4 = ((const float4*)beta)[t];
    float4 o4;
    o4.x = (r0 - mu) * inv * g4.x + b4.x;
    o4.y = (r1 - mu) * inv * g4.y + b4.y;
    o4.z = (r2 - mu) * inv * g4.z + b4.z;
    o4.w = (r3 - mu) * inv * g4.w + b4.w;
    ((float4*)(out + (size_t)row * 1024))[t] = o4;
}

extern "C" void kernel_launch(void* const* d_in, const int* in_sizes, int n_in,
                              void* d_out, int out_size, void* d_ws, size_t ws_size,
                              hipStream_t stream) {
    const float* x     = (const float*)d_in[0];
    const float* mask  = (const float*)d_in[1];
    const float* Wq    = (const float*)d_in[2];
    const float* bq    = (const float*)d_in[3];
    const float* Wk    = (const float*)d_in[4];
    const float* bk    = (const float*)d_in[5];
    const float* Wv    = (const float*)d_in[6];
    const float* bv    = (const float*)d_in[7];
    const float* Wo    = (const float*)d_in[8];
    const float* bo    = (const float*)d_in[9];
    const float* gamma = (const float*)d_in[10];
    const float* beta  = (const float*)d_in[11];
    float* out = (float*)d_out;

    char* ws = (char*)d_ws;
    ushortT* Xb  = (ushortT*)(ws);
    ushortT* Wqb = (ushortT*)(ws + (16u << 20));
    ushortT* Wkb = (ushortT*)(ws + (18u << 20));
    ushortT* Wvb = (ushortT*)(ws + (20u << 20));
    ushortT* Wob = (ushortT*)(ws + (22u << 20));
    ushortT* Qb  = (ushortT*)(ws + (24u << 20));
    ushortT* Kb  = (ushortT*)(ws + (40u << 20));
    ushortT* Vb  = (ushortT*)(ws + (56u << 20));  // V^T [bh][d][s]
    ushortT* Cb  = (ushortT*)(ws);                // ctx reuses Xb
    float*   Pj  = (float*)(ws + (24u << 20));    // fp32 proj reuses Q/K

    cvt_x<<<8192, 256, 0, stream>>>(x, Xb, 2097152);
    cvt_w<<<dim3(1024, 4), 256, 0, stream>>>(Wq, Wk, Wv, Wo, Wqb, Wkb, Wvb, Wob, 262144);
    qkv256<<<384, 512, 0, stream>>>(Xb, Wqb, Wkb, Wvb, bq, bk, bv, Qb, Kb, Vb);
    attn_kernel<<<512, 256, 0, stream>>>(Qb, Kb, Vb, mask, Cb);
    oproj_gemm<<<512, 256, 0, stream>>>(Cb, Wob, bo, Pj);
    ln_kernel<<<8192, 256, 0, stream>>>(Pj, x, gamma, beta, out);
}